// Round 13
// baseline (117.754 us; speedup 1.0000x reference)
//
#include <hip/hip_runtime.h>

#define RANK 16
#define N 512

typedef float vfloat4 __attribute__((ext_vector_type(4)));

// Fill-identical chip-wide sweep, de-confounded: row r = 2048*j + wp, so at
// each j the whole grid writes one dense 4 MB window marching monotonically
// through the 512 MB output (the exact pattern fill sustains 6.6+ TB/s on).
// Inner loop has ZERO global loads: f0 staged in LDS (32 KB), f1 column and
// f2 fragment in registers.
__global__ __launch_bounds__(256, 4) void parafac_kernel(
    const float* __restrict__ f0,
    const float* __restrict__ f1,
    const float* __restrict__ f2,
    float* __restrict__ out)
{
    __shared__ float f0s[RANK][N];               // all of f0: 32 KB

    const int t    = threadIdx.x;
    const int wave = t >> 6;                     // 0..3
    const int lane = t & 63;
    const int wp   = blockIdx.x * 2 + (wave >> 1);   // global wave-pair 0..2047
    const int b    = wp & (N - 1);               // fixed b per wave-pair
    const int a0   = wp >> 9;                    // 0..3
    const int c4   = (wave & 1) * 256 + lane * 4;    // c-half per wave parity

    // ---- Stage ALL of f0 into LDS, coalesced (8 x 1 KB wave-contiguous) ----
#pragma unroll
    for (int i = 0; i < 8; ++i) {
        const int idx = t * 4 + i * 1024;
        *reinterpret_cast<vfloat4*>(&f0s[0][0] + idx) =
            *reinterpret_cast<const vfloat4*>(f0 + idx);
    }

    // f1 column b: 16 loop-invariant wave-uniform scalars in registers.
    float f1b[RANK];
#pragma unroll
    for (int k = 0; k < RANK; ++k) f1b[k] = f1[k * N + b];

    // f2 fragment: 16 x vfloat4 (64 VGPRs), loaded once.
    vfloat4 v[RANK];
#pragma unroll
    for (int k = 0; k < RANK; ++k)
        v[k] = *reinterpret_cast<const vfloat4*>(&f2[k * N + c4]);

    __syncthreads();   // only barrier: f0s visible to all

    // Row r = 2048*j + wp; store address advances 4 MB per iteration.
    float* o = out + (size_t)wp * N + c4;
    int a = a0;

#pragma unroll 2
    for (int j = 0; j < 128; ++j) {
        vfloat4 acc = (vfloat4)(0.f);
#pragma unroll
        for (int k = 0; k < RANK; ++k) {
            const float pk = f0s[k][a] * f1b[k];   // broadcast ds_read_b32
            acc += pk * v[k];
        }
        *reinterpret_cast<vfloat4*>(o) = acc;       // 1 KB contiguous per wave
        o += (size_t)2048 * N;                      // next chip-wide window
        a += 4;
    }
}

extern "C" void kernel_launch(void* const* d_in, const int* in_sizes, int n_in,
                              void* d_out, int out_size, void* d_ws, size_t ws_size,
                              hipStream_t stream) {
    const float* f0 = (const float*)d_in[0];
    const float* f1 = (const float*)d_in[1];
    const float* f2 = (const float*)d_in[2];
    float* out = (float*)d_out;

    dim3 grid(1024);    // 2048 wave-pairs; 4 blocks/CU, 16 waves/CU
    dim3 block(256);
    parafac_kernel<<<grid, block, 0, stream>>>(f0, f1, f2, out);
}

// Round 14
// 109.815 us; speedup vs baseline: 1.0723x; 1.0723x over previous
//
#include <hip/hip_runtime.h>

#define RANK 16
#define N 512
#define BTILE 64
#define NBLK (N / BTILE)          // 8 b-tiles per a
#define CPB 4                     // chunks per block (consecutive -> 512 KB/block)
#define GRID (N * NBLK / CPB)     // 1024 blocks

typedef float vfloat4 __attribute__((ext_vector_type(4)));

__global__ __launch_bounds__(256) void parafac_kernel(
    const float* __restrict__ f0,
    const float* __restrict__ f1,
    const float* __restrict__ f2,
    float* __restrict__ out)
{
    __shared__ float pt[BTILE][RANK];   // b-major rank products, 4 KB

    const int t     = threadIdx.x;
    const int wave  = t >> 6;           // 0..3
    const int lane  = t & 63;
    const int wp2   = wave >> 1;        // wave pair: row offset within quad
    const int c4    = (wave & 1) * 256 + lane * 4;

    // f2 fragment resident in registers: 16 x float4 (64 VGPRs), loaded ONCE.
    vfloat4 v[RANK];
#pragma unroll
    for (int k = 0; k < RANK; ++k)
        v[k] = *reinterpret_cast<const vfloat4*>(&f2[k * N + c4]);

    // Staging indices: thread t covers row r = t&63, k-quad kq = t>>6.
    const int sr  = t & 63;
    const int skq = (t >> 6) * 4;

    for (int ci = 0; ci < CPB; ++ci) {
        const int cid = blockIdx.x * CPB + ci;   // consecutive output regions
        const int a   = cid / NBLK;
        const int b0  = (cid % NBLK) * BTILE;

        // Stage pt[r][k] = f0[k][a] * f1[k][b0+r] (b-major; f1 loads coalesced)
        {
            vfloat4 w;
#pragma unroll
            for (int j = 0; j < 4; ++j) {
                const int k = skq + j;
                w[j] = f0[k * N + a] * f1[k * N + b0 + sr];
            }
            *reinterpret_cast<vfloat4*>(&pt[sr][skq]) = w;
        }
        __syncthreads();

        float* outa = out + ((size_t)a * N + b0) * N + c4;

        // 16 lockstep iterations; per iteration the block writes 4 CONSECUTIVE
        // rows (one contiguous 8 KB window). Wave pair wp2 takes rows
        // 4it + 2*wp2 + {0,1}, each wave its c-half. pt read-only within the
        // chunk -> raw s_barrier, no waitcnt drain.
#pragma unroll
        for (int it = 0; it < BTILE / 4; ++it) {
            if (it != 0) __builtin_amdgcn_s_barrier();
            const int r0 = it * 4 + wp2 * 2;
            const vfloat4* pr0 = reinterpret_cast<const vfloat4*>(&pt[r0][0]);
            const vfloat4* pr1 = reinterpret_cast<const vfloat4*>(&pt[r0 + 1][0]);
            vfloat4 acc0 = (vfloat4)(0.f);
            vfloat4 acc1 = (vfloat4)(0.f);
#pragma unroll
            for (int q = 0; q < 4; ++q) {
                const vfloat4 p0 = pr0[q];       // broadcast ds_read_b128
                const vfloat4 p1 = pr1[q];
#pragma unroll
                for (int j = 0; j < 4; ++j) {
                    acc0 += p0[j] * v[q * 4 + j];
                    acc1 += p1[j] * v[q * 4 + j];
                }
            }
            float* o = outa + (size_t)r0 * N;
            *reinterpret_cast<vfloat4*>(o)     = acc0;
            *reinterpret_cast<vfloat4*>(o + N) = acc1;
        }
        __syncthreads();   // pt reused next chunk
    }
}

extern "C" void kernel_launch(void* const* d_in, const int* in_sizes, int n_in,
                              void* d_out, int out_size, void* d_ws, size_t ws_size,
                              hipStream_t stream) {
    const float* f0 = (const float*)d_in[0];
    const float* f1 = (const float*)d_in[1];
    const float* f2 = (const float*)d_in[2];
    float* out = (float*)d_out;

    dim3 grid(GRID);    // 1024 blocks
    dim3 block(256);
    parafac_kernel<<<grid, block, 0, stream>>>(f0, f1, f2, out);
}

// Round 15
// 97.719 us; speedup vs baseline: 1.2050x; 1.1238x over previous
//
#include <hip/hip_runtime.h>

#define RANK 16
#define N 512
#define BTILE 64
#define NBLK (N / BTILE)          // 8 b-tiles per a
#define CPB 4                     // consecutive chunks per block (512 KB/block)
#define GRID (N * NBLK / CPB)     // 1024 blocks

typedef float vfloat4 __attribute__((ext_vector_type(4)));

__global__ __launch_bounds__(256) void parafac_kernel(
    const float* __restrict__ f0,
    const float* __restrict__ f1,
    const float* __restrict__ f2,
    float* __restrict__ out)
{
    __shared__ float pt[BTILE][RANK];   // b-major rank products, 4 KB

    const int t     = threadIdx.x;
    const int wave  = t >> 6;           // 0..3
    const int lane  = t & 63;
    const int rbase = (wave >> 1) * 32; // R12's wave-pair strip mapping
    const int c4    = (wave & 1) * 256 + lane * 4;

    // f2 fragment resident in registers: 16 x float4 (64 VGPRs), loaded ONCE.
    vfloat4 v[RANK];
#pragma unroll
    for (int k = 0; k < RANK; ++k)
        v[k] = *reinterpret_cast<const vfloat4*>(&f2[k * N + c4]);

    // Staging indices: thread t covers row r = t&63, k-quad kq = t>>6.
    const int sr  = t & 63;
    const int skq = (t >> 6) * 4;

    for (int ci = 0; ci < CPB; ++ci) {
        const int cid = blockIdx.x * CPB + ci;
        const int a   = cid / NBLK;
        const int b0  = (cid % NBLK) * BTILE;

        // Stage pt[r][k] = f0[k][a] * f1[k][b0+r] (b-major, coalesced f1 reads)
        {
            vfloat4 w;
#pragma unroll
            for (int j = 0; j < 4; ++j) {
                const int k = skq + j;
                w[j] = f0[k * N + a] * f1[k * N + b0 + sr];
            }
            *reinterpret_cast<vfloat4*>(&pt[sr][skq]) = w;
        }
        __syncthreads();

        float* outa = out + ((size_t)a * N + b0) * N + c4;

        // R12's cadence: 8 lockstep iterations x 4 rows per wave. Difference:
        // rows processed SEQUENTIALLY so each store issues as soon as its row
        // finishes -> store issue spread through the iteration, not bunched.
#pragma unroll
        for (int it = 0; it < 8; ++it) {
            if (it != 0) __builtin_amdgcn_s_barrier();
            const int r0 = rbase + it * 4;
#pragma unroll
            for (int r = 0; r < 4; ++r) {
                const vfloat4* pr = reinterpret_cast<const vfloat4*>(&pt[r0 + r][0]);
                const vfloat4 p0 = pr[0];   // broadcast ds_read_b128 x4
                const vfloat4 p1 = pr[1];
                const vfloat4 p2 = pr[2];
                const vfloat4 p3 = pr[3];
                // split accumulators: two independent chains, merged at store
                vfloat4 accA = (vfloat4)(0.f);
                vfloat4 accB = (vfloat4)(0.f);
#pragma unroll
                for (int j = 0; j < 4; ++j) {
                    accA += p0[j] * v[j];
                    accB += p1[j] * v[4 + j];
                    accA += p2[j] * v[8 + j];
                    accB += p3[j] * v[12 + j];
                }
                *reinterpret_cast<vfloat4*>(outa + (size_t)(r0 + r) * N) = accA + accB;
            }
        }
        __syncthreads();   // pt reused next chunk
    }
}

extern "C" void kernel_launch(void* const* d_in, const int* in_sizes, int n_in,
                              void* d_out, int out_size, void* d_ws, size_t ws_size,
                              hipStream_t stream) {
    const float* f0 = (const float*)d_in[0];
    const float* f1 = (const float*)d_in[1];
    const float* f2 = (const float*)d_in[2];
    float* out = (float*)d_out;

    dim3 grid(GRID);    // 1024 blocks
    dim3 block(256);
    parafac_kernel<<<grid, block, 0, stream>>>(f0, f1, f2, out);
}

// Round 16
// 97.313 us; speedup vs baseline: 1.2101x; 1.0042x over previous
//
#include <hip/hip_runtime.h>

#define RANK 16
#define N 512
#define BTILE 64
#define NBLK (N / BTILE)          // 8 b-tiles per a
#define CPB 4                     // consecutive chunks per block (512 KB/block)
#define GRID (N * NBLK / CPB)     // 1024 blocks

typedef float vfloat4 __attribute__((ext_vector_type(4)));

__global__ __launch_bounds__(256) void parafac_kernel(
    const float* __restrict__ f0,
    const float* __restrict__ f1,
    const float* __restrict__ f2,
    float* __restrict__ out)
{
    __shared__ float pt[BTILE][RANK];   // b-major rank products, 4 KB

    const int t     = threadIdx.x;
    const int wave  = t >> 6;           // 0..3
    const int lane  = t & 63;
    const int rbase = (wave >> 1) * 32; // wave-pair strip (R12/R15 mapping)
    const int c4    = (wave & 1) * 256 + lane * 4;

    // f2 fragment resident in registers: 16 x float4 (64 VGPRs), loaded ONCE.
    vfloat4 v[RANK];
#pragma unroll
    for (int k = 0; k < RANK; ++k)
        v[k] = *reinterpret_cast<const vfloat4*>(&f2[k * N + c4]);

    // Staging indices: thread t covers row r = t&63, k-quad kq = t>>6.
    const int sr  = t & 63;
    const int skq = (t >> 6) * 4;

    for (int ci = 0; ci < CPB; ++ci) {
        const int cid = blockIdx.x * CPB + ci;
        const int a   = cid / NBLK;
        const int b0  = (cid % NBLK) * BTILE;

        // Stage pt[r][k] = f0[k][a] * f1[k][b0+r] (b-major, coalesced f1 reads)
        {
            vfloat4 w;
#pragma unroll
            for (int j = 0; j < 4; ++j) {
                const int k = skq + j;
                w[j] = f0[k * N + a] * f1[k * N + b0 + sr];
            }
            *reinterpret_cast<vfloat4*>(&pt[sr][skq]) = w;
        }
        __syncthreads();

        float* outa = out + ((size_t)a * N + b0) * N + c4;

        // R15's structure, 2x finer lockstep cadence: barrier every 2 rows
        // per wave. Per-row store spreading unchanged.
#pragma unroll
        for (int it = 0; it < 16; ++it) {
            if (it != 0) __builtin_amdgcn_s_barrier();
            const int r0 = rbase + it * 2;
#pragma unroll
            for (int r = 0; r < 2; ++r) {
                const vfloat4* pr = reinterpret_cast<const vfloat4*>(&pt[r0 + r][0]);
                const vfloat4 p0 = pr[0];   // broadcast ds_read_b128 x4
                const vfloat4 p1 = pr[1];
                const vfloat4 p2 = pr[2];
                const vfloat4 p3 = pr[3];
                vfloat4 accA = (vfloat4)(0.f);
                vfloat4 accB = (vfloat4)(0.f);
#pragma unroll
                for (int j = 0; j < 4; ++j) {
                    accA += p0[j] * v[j];
                    accB += p1[j] * v[4 + j];
                    accA += p2[j] * v[8 + j];
                    accB += p3[j] * v[12 + j];
                }
                *reinterpret_cast<vfloat4*>(outa + (size_t)(r0 + r) * N) = accA + accB;
            }
        }
        __syncthreads();   // pt reused next chunk
    }
}

extern "C" void kernel_launch(void* const* d_in, const int* in_sizes, int n_in,
                              void* d_out, int out_size, void* d_ws, size_t ws_size,
                              hipStream_t stream) {
    const float* f0 = (const float*)d_in[0];
    const float* f1 = (const float*)d_in[1];
    const float* f2 = (const float*)d_in[2];
    float* out = (float*)d_out;

    dim3 grid(GRID);    // 1024 blocks
    dim3 block(256);
    parafac_kernel<<<grid, block, 0, stream>>>(f0, f1, f2, out);
}